// Round 2
// 697.475 us; speedup vs baseline: 1.0249x; 1.0249x over previous
//
#include <hip/hip_runtime.h>

#define N_NODES  50000
#define N_EDGES  800000
#define D_IN     64
#define D_RADIAL 128
#define NTILES   (N_EDGES / 64)   // 12500, exact

typedef __bf16 bf16x8 __attribute__((ext_vector_type(8)));
typedef float  f32x4  __attribute__((ext_vector_type(4)));
typedef short  s16x8  __attribute__((ext_vector_type(8)));

// pack two f32 -> two bf16 (truncation) in one v_perm (MFMA inputs)
__device__ inline unsigned int pack_bf16_pair(float lo, float hi) {
    return __builtin_amdgcn_perm(__float_as_uint(hi), __float_as_uint(lo), 0x07060302u);
}

// round-to-nearest-even f32 -> bf16
__device__ inline unsigned short f2bf_rne(float f) {
    unsigned int u = __float_as_uint(f);
    u += 0x7FFFu + ((u >> 16) & 1u);
    return (unsigned short)(u >> 16);
}

// ---------------- workspace layout (CSR path) ----------------
constexpr size_t ws_align(size_t x) { return (x + 255) & ~(size_t)255; }
constexpr size_t WS_CNT  = 0;                                          // int[N_NODES]     edge counts per dst
constexpr size_t WS_OFF  = ws_align(WS_CNT  + (size_t)N_NODES * 4);    // int[N_NODES+1]   exclusive offsets
constexpr size_t WS_CUR  = ws_align(WS_OFF  + (size_t)(N_NODES + 1) * 4); // int[N_NODES]  scatter cursors
constexpr size_t WS_BSUM = ws_align(WS_CUR  + (size_t)N_NODES * 4);    // int[128]         scan block sums
constexpr size_t WS_RANK = ws_align(WS_BSUM + 512);                    // int[N_EDGES]     dst-sorted position of edge e
constexpr size_t WS_MSG  = ws_align(WS_RANK + (size_t)N_EDGES * 4);    // ushort[N_EDGES*64] bf16 messages, dst-sorted rows
constexpr size_t WS_REQUIRED = WS_MSG + (size_t)N_EDGES * D_IN * 2;    // ~106 MB

#define SCAN_B    512
#define SCAN_NBLK ((N_NODES + SCAN_B - 1) / SCAN_B)   // 98
static_assert(SCAN_NBLK <= 128, "scan_tops assumes <=128 blocks");

// ---------------- sort kernels ----------------
__global__ __launch_bounds__(256) void hist_kernel(const int* __restrict__ dst,
                                                   int* __restrict__ cnt) {
    int i = blockIdx.x * 256 + threadIdx.x;
    if (i < N_EDGES) atomicAdd(&cnt[dst[i]], 1);
}

__global__ __launch_bounds__(SCAN_B) void scan_block(const int* __restrict__ cnt,
                                                     int* __restrict__ offs,
                                                     int* __restrict__ bsum) {
    const int t = threadIdx.x, b = blockIdx.x;
    const int i = b * SCAN_B + t;
    int v = (i < N_NODES) ? cnt[i] : 0;
    __shared__ int s[SCAN_B];
    s[t] = v;
    __syncthreads();
    for (int o = 1; o < SCAN_B; o <<= 1) {
        int add = (t >= o) ? s[t - o] : 0;
        __syncthreads();
        s[t] += add;
        __syncthreads();
    }
    if (i < N_NODES) offs[i] = s[t];          // inclusive within block (temporary)
    if (t == SCAN_B - 1) bsum[b] = s[t];
}

__global__ __launch_bounds__(128) void scan_tops(int* __restrict__ bsum) {
    const int t = threadIdx.x;
    __shared__ int s[128];
    int v = (t < SCAN_NBLK) ? bsum[t] : 0;
    s[t] = v;
    __syncthreads();
    for (int o = 1; o < 128; o <<= 1) {
        int add = (t >= o) ? s[t - o] : 0;
        __syncthreads();
        s[t] += add;
        __syncthreads();
    }
    if (t < SCAN_NBLK) bsum[t] = s[t] - v;    // exclusive
}

__global__ __launch_bounds__(SCAN_B) void finalize_off(const int* __restrict__ cnt,
                                                       int* __restrict__ offs,
                                                       const int* __restrict__ bsum,
                                                       int* __restrict__ cur) {
    const int i = blockIdx.x * SCAN_B + threadIdx.x;
    if (i < N_NODES) {
        int e = offs[i] - cnt[i] + bsum[blockIdx.x];   // global exclusive prefix
        offs[i] = e;
        cur[i]  = e;
    }
    if (i == 0) offs[N_NODES] = N_EDGES;
}

__global__ __launch_bounds__(256) void scatter_rank(const int* __restrict__ dst,
                                                    int* __restrict__ cur,
                                                    int* __restrict__ rank) {
    int i = blockIdx.x * 256 + threadIdx.x;
    if (i < N_EDGES) rank[i] = atomicAdd(&cur[dst[i]], 1);
}

// ---------------- phase A: MFMA filter + x-gather -> bf16 msg rows (dst-sorted) ----------------
__global__ __launch_bounds__(256) void msg_kernel(
    const float* __restrict__ x,        // [N, 64]
    const float* __restrict__ eb,       // [E, 128]
    const int*   __restrict__ src,      // [E]
    const int*   __restrict__ rank,     // [E] dst-sorted position
    const float* __restrict__ W,        // [64, 128]
    const float* __restrict__ bias_p,   // [64]
    unsigned short* __restrict__ msg)   // [E, 64] bf16, row j = j-th dst-sorted edge
{
    const int lane = threadIdx.x & 63;
    const int wv   = threadIdx.x >> 6;
    const int l15  = lane & 15;
    const int quad = lane >> 4;

    // B-operand fragments of W' (W'[r][d] = W[d][r]); loaded once per block
    bf16x8 wfrag[4][4];
    #pragma unroll
    for (int nt = 0; nt < 4; ++nt) {
        const int d = nt * 16 + l15;
        #pragma unroll
        for (int kt = 0; kt < 4; ++kt) {
            const float* p = W + d * D_RADIAL + kt * 32 + quad * 8;
            s16x8 s;
            #pragma unroll
            for (int j = 0; j < 8; ++j) s[j] = (short)f2bf_rne(p[j]);
            wfrag[nt][kt] = __builtin_bit_cast(bf16x8, s);
        }
    }
    float bv[4];
    #pragma unroll
    for (int nt = 0; nt < 4; ++nt) bv[nt] = bias_p[nt * 16 + l15];

    for (int tile = blockIdx.x; tile < NTILES; tile += gridDim.x) {
        const int ebase = tile * 64 + wv * 16;   // this wave's 16 edges
        const int erow  = ebase + quad * 4;

        // issue index loads early; they overlap the eb stream + MFMA
        int sv[4], rk[4];
        #pragma unroll
        for (int reg = 0; reg < 4; ++reg) {
            sv[reg] = src[erow + reg];
            rk[reg] = rank[erow + reg];
        }

        f32x4 acc[4];
        #pragma unroll
        for (int nt = 0; nt < 4; ++nt) acc[nt] = (f32x4){0.f, 0.f, 0.f, 0.f};

        #pragma unroll
        for (int kt = 0; kt < 4; ++kt) {
            const float* p = eb + (long)(ebase + l15) * D_RADIAL + kt * 32 + quad * 8;
            f32x4 a0 = *(const f32x4*)(p);
            f32x4 a1 = *(const f32x4*)(p + 4);
            int4 packed;
            packed.x = pack_bf16_pair(a0[0], a0[1]);
            packed.y = pack_bf16_pair(a0[2], a0[3]);
            packed.z = pack_bf16_pair(a1[0], a1[1]);
            packed.w = pack_bf16_pair(a1[2], a1[3]);
            bf16x8 afrag = __builtin_bit_cast(bf16x8, packed);
            #pragma unroll
            for (int nt = 0; nt < 4; ++nt)
                acc[nt] = __builtin_amdgcn_mfma_f32_16x16x32_bf16(
                    afrag, wfrag[nt][kt], acc[nt], 0, 0, 0);
        }

        // D[row=quad*4+reg][col=l15]; store message at dst-sorted row rk
        #pragma unroll
        for (int reg = 0; reg < 4; ++reg) {
            const float*    xrow = x   + (long)sv[reg] * D_IN;
            unsigned short* mrow = msg + (long)rk[reg] * D_IN;
            #pragma unroll
            for (int nt = 0; nt < 4; ++nt) {
                const int d = nt * 16 + l15;
                mrow[d] = f2bf_rne((acc[nt][reg] + bv[nt]) * xrow[d]);
            }
        }
    }
}

// ---------------- phase B: per-node wave, stream contiguous sorted rows, one store ----------------
__global__ __launch_bounds__(256) void gather_out(
    const unsigned short* __restrict__ msg,
    const int* __restrict__ offs,
    float* __restrict__ out)
{
    const int lane = threadIdx.x & 63;
    const int wid  = blockIdx.x * 4 + (threadIdx.x >> 6);
    const int wstr = gridDim.x * 4;
    for (int n = wid; n < N_NODES; n += wstr) {
        const int j0 = offs[n], j1 = offs[n + 1];
        const unsigned short* p = msg + (size_t)j0 * D_IN + lane;
        float a0 = 0.f, a1 = 0.f, a2 = 0.f, a3 = 0.f;
        int j = j0;
        for (; j + 4 <= j1; j += 4, p += 4 * D_IN) {
            a0 += __uint_as_float((unsigned int)p[0]        << 16);
            a1 += __uint_as_float((unsigned int)p[D_IN]     << 16);
            a2 += __uint_as_float((unsigned int)p[2 * D_IN] << 16);
            a3 += __uint_as_float((unsigned int)p[3 * D_IN] << 16);
        }
        for (; j < j1; ++j, p += D_IN)
            a0 += __uint_as_float((unsigned int)p[0] << 16);
        out[(size_t)n * D_IN + lane] = (a0 + a1) + (a2 + a3);
    }
}

// ---------------- legacy fallback (atomic) kernel — unchanged ----------------
__global__ __launch_bounds__(256) void edge_msg_kernel(
    const float* __restrict__ x,
    const float* __restrict__ eb,
    const int*   __restrict__ src,
    const int*   __restrict__ dst,
    const float* __restrict__ W,
    const float* __restrict__ bias_p,
    float*       __restrict__ out)
{
    const int lane = threadIdx.x & 63;
    const int wv   = threadIdx.x >> 6;
    const int l15  = lane & 15;
    const int quad = lane >> 4;

    bf16x8 wfrag[4][4];
    #pragma unroll
    for (int nt = 0; nt < 4; ++nt) {
        const int d = nt * 16 + l15;
        #pragma unroll
        for (int kt = 0; kt < 4; ++kt) {
            const float* p = W + d * D_RADIAL + kt * 32 + quad * 8;
            s16x8 s;
            #pragma unroll
            for (int j = 0; j < 8; ++j) s[j] = (short)f2bf_rne(p[j]);
            wfrag[nt][kt] = __builtin_bit_cast(bf16x8, s);
        }
    }
    float bv[4];
    #pragma unroll
    for (int nt = 0; nt < 4; ++nt) bv[nt] = bias_p[nt * 16 + l15];

    for (int tile = blockIdx.x; tile < NTILES; tile += gridDim.x) {
        const int ebase = tile * 64 + wv * 16;

        f32x4 acc[4];
        #pragma unroll
        for (int nt = 0; nt < 4; ++nt) acc[nt] = (f32x4){0.f, 0.f, 0.f, 0.f};

        #pragma unroll
        for (int kt = 0; kt < 4; ++kt) {
            const float* p = eb + (long)(ebase + l15) * D_RADIAL + kt * 32 + quad * 8;
            f32x4 a0 = *(const f32x4*)(p);
            f32x4 a1 = *(const f32x4*)(p + 4);
            int4 packed;
            packed.x = pack_bf16_pair(a0[0], a0[1]);
            packed.y = pack_bf16_pair(a0[2], a0[3]);
            packed.z = pack_bf16_pair(a1[0], a1[1]);
            packed.w = pack_bf16_pair(a1[2], a1[3]);
            bf16x8 afrag = __builtin_bit_cast(bf16x8, packed);
            #pragma unroll
            for (int nt = 0; nt < 4; ++nt)
                acc[nt] = __builtin_amdgcn_mfma_f32_16x16x32_bf16(
                    afrag, wfrag[nt][kt], acc[nt], 0, 0, 0);
        }

        const int erow = ebase + quad * 4;
        #pragma unroll
        for (int reg = 0; reg < 4; ++reg) {
            const int e  = erow + reg;
            const int sv = src[e];
            const int dv = dst[e];
            const float* xrow = x   + (long)sv * D_IN;
            float*       orow = out + (long)dv * D_IN;
            #pragma unroll
            for (int nt = 0; nt < 4; ++nt) {
                const int d = nt * 16 + l15;
                const float val = (acc[nt][reg] + bv[nt]) * xrow[d];
                unsafeAtomicAdd(orow + d, val);
            }
        }
    }
}

extern "C" void kernel_launch(void* const* d_in, const int* in_sizes, int n_in,
                              void* d_out, int out_size, void* d_ws, size_t ws_size,
                              hipStream_t stream) {
    const float* x    = (const float*)d_in[0];
    const float* eb   = (const float*)d_in[1];
    const int*   src  = (const int*)d_in[2];
    const int*   dst  = (const int*)d_in[3];
    const float* W    = (const float*)d_in[4];
    const float* bias = (const float*)d_in[5];
    float* out = (float*)d_out;

    if (ws_size >= WS_REQUIRED) {
        // CSR two-phase path: no float atomics anywhere
        char* ws   = (char*)d_ws;
        int*  cnt  = (int*)(ws + WS_CNT);
        int*  offs = (int*)(ws + WS_OFF);
        int*  cur  = (int*)(ws + WS_CUR);
        int*  bsum = (int*)(ws + WS_BSUM);
        int*  rank = (int*)(ws + WS_RANK);
        unsigned short* msg = (unsigned short*)(ws + WS_MSG);

        hipMemsetAsync(cnt, 0, (size_t)N_NODES * 4, stream);
        hist_kernel  <<<(N_EDGES + 255) / 256, 256, 0, stream>>>(dst, cnt);
        scan_block   <<<SCAN_NBLK, SCAN_B, 0, stream>>>(cnt, offs, bsum);
        scan_tops    <<<1, 128, 0, stream>>>(bsum);
        finalize_off <<<SCAN_NBLK, SCAN_B, 0, stream>>>(cnt, offs, bsum, cur);
        scatter_rank <<<(N_EDGES + 255) / 256, 256, 0, stream>>>(dst, cur, rank);
        // 1280 blocks = 5 blocks/CU co-resident at 88 VGPR (5 waves/SIMD)
        msg_kernel   <<<1280, 256, 0, stream>>>(x, eb, src, rank, W, bias, msg);
        // gather_out writes every output element -> no d_out memset needed
        gather_out   <<<1024, 256, 0, stream>>>(msg, offs, out);
    } else {
        // fallback: original atomic kernel (harness poisons d_out -> zero it first)
        hipMemsetAsync(d_out, 0, (size_t)N_NODES * D_IN * sizeof(float), stream);
        edge_msg_kernel<<<1024, 256, 0, stream>>>(x, eb, src, dst, W, bias, out);
    }
}